// Round 3
// baseline (273.159 us; speedup 1.0000x reference)
//
#include <hip/hip_runtime.h>

typedef __bf16 bf16x8 __attribute__((ext_vector_type(8)));
typedef float  f32x4  __attribute__((ext_vector_type(4)));

struct KArgs {
    const float* x[6];
    const float* W[6];
    const float* b[6];
    float*       out[6];
    int nrows[6];
    int blk0[7];   // cumulative block offsets per type
};

// Wave-autonomous, barrier-free, LDS-free.
// Block = 256 threads = 4 waves. wave>>1 = row-group (16 rows), wave&1 = col half.
// A = W (M = output col, in registers as bf16), B = x (N = x-row, global->reg->cvt).
// D lane map (m89): col(l15) = x-row, row(lq*4+r) = out col -> float4 stores.
template<int FIN>
__device__ __forceinline__ void run_type(
    const float* __restrict__ x, const float* __restrict__ W,
    const float* __restrict__ bias, float* __restrict__ out,
    int nrows, int c0, int c1)
{
    constexpr int NC = FIN / 32;      // k-fragments

    const int tid     = threadIdx.x;
    const int lane    = tid & 63;
    const int wave    = tid >> 6;
    const int l15     = lane & 15;
    const int lq      = lane >> 4;
    const int rowgrp  = wave >> 1;            // 0,1
    const int colbase = (wave & 1) * 64;      // 0 or 64

    // ---- W fragments (A operand), fp32 -> bf16 once. Wf[c][t]: col-tile t.
    bf16x8 Wf[NC][4];
    #pragma unroll
    for (int t = 0; t < 4; ++t) {
        const int o = colbase + t * 16 + l15;          // output col = W row
        #pragma unroll
        for (int c = 0; c < NC; ++c) {
            const f32x4 w0 = *(const f32x4*)(W + (size_t)o * FIN + c * 32 + lq * 8);
            const f32x4 w1 = *(const f32x4*)(W + (size_t)o * FIN + c * 32 + lq * 8 + 4);
            bf16x8 f;
            f[0] = (__bf16)w0[0]; f[1] = (__bf16)w0[1];
            f[2] = (__bf16)w0[2]; f[3] = (__bf16)w0[3];
            f[4] = (__bf16)w1[0]; f[5] = (__bf16)w1[1];
            f[6] = (__bf16)w1[2]; f[7] = (__bf16)w1[3];
            Wf[c][t] = f;
        }
    }
    f32x4 bv[4];
    #pragma unroll
    for (int t = 0; t < 4; ++t)
        bv[t] = *(const f32x4*)(bias + colbase + t * 16 + lq * 4);

    // ---- chunk loop: 32 rows per chunk (16 per row-group). No barriers.
    for (int chunk = c0; chunk < c1; ++chunk) {
        const int xrow = chunk * 32 + rowgrp * 16 + l15;
        const int gr   = (xrow < nrows) ? xrow : (nrows - 1);   // clamp; store guarded
        const float* xp = x + (size_t)gr * FIN;

        f32x4 acc[4] = {};
        #pragma unroll
        for (int c = 0; c < NC; ++c) {
            const f32x4 v0 = __builtin_nontemporal_load((const f32x4*)(xp + c * 32 + lq * 8));
            const f32x4 v1 = __builtin_nontemporal_load((const f32x4*)(xp + c * 32 + lq * 8 + 4));
            bf16x8 xc;
            xc[0] = (__bf16)v0[0]; xc[1] = (__bf16)v0[1];
            xc[2] = (__bf16)v0[2]; xc[3] = (__bf16)v0[3];
            xc[4] = (__bf16)v1[0]; xc[5] = (__bf16)v1[1];
            xc[6] = (__bf16)v1[2]; xc[7] = (__bf16)v1[3];
            acc[0] = __builtin_amdgcn_mfma_f32_16x16x32_bf16(Wf[c][0], xc, acc[0], 0, 0, 0);
            acc[1] = __builtin_amdgcn_mfma_f32_16x16x32_bf16(Wf[c][1], xc, acc[1], 0, 0, 0);
            acc[2] = __builtin_amdgcn_mfma_f32_16x16x32_bf16(Wf[c][2], xc, acc[2], 0, 0, 0);
            acc[3] = __builtin_amdgcn_mfma_f32_16x16x32_bf16(Wf[c][3], xc, acc[3], 0, 0, 0);
        }

        if (xrow < nrows) {
            float* op = out + (size_t)xrow * 128 + colbase;
            #pragma unroll
            for (int t = 0; t < 4; ++t)
                __builtin_nontemporal_store(acc[t] + bv[t], (f32x4*)(op + t * 16 + lq * 4));
        }
    }
}

__global__ __launch_bounds__(256, 2) void hetero_fused_kern(KArgs A)
{
    int ty = 0;
    const int bid = blockIdx.x;
    while (ty < 5 && bid >= A.blk0[ty + 1]) ++ty;
    const int lb = bid - A.blk0[ty];
    const int nb = A.blk0[ty + 1] - A.blk0[ty];

    const int nrows  = A.nrows[ty];
    const int chunks = (nrows + 31) >> 5;
    const int c0 = (int)(((long)chunks * lb) / nb);
    const int c1 = (int)(((long)chunks * (lb + 1)) / nb);
    if (c0 >= c1) return;

    switch (ty) {
        case 0: run_type<128>(A.x[0], A.W[0], A.b[0], A.out[0], nrows, c0, c1); break;
        case 1: run_type<256>(A.x[1], A.W[1], A.b[1], A.out[1], nrows, c0, c1); break;
        case 2: run_type< 64>(A.x[2], A.W[2], A.b[2], A.out[2], nrows, c0, c1); break;
        case 3: run_type<128>(A.x[3], A.W[3], A.b[3], A.out[3], nrows, c0, c1); break;
        case 4: run_type< 64>(A.x[4], A.W[4], A.b[4], A.out[4], nrows, c0, c1); break;
        case 5: run_type<128>(A.x[5], A.W[5], A.b[5], A.out[5], nrows, c0, c1); break;
    }
}

extern "C" void kernel_launch(void* const* d_in, const int* in_sizes, int n_in,
                              void* d_out, int out_size, void* d_ws, size_t ws_size,
                              hipStream_t stream)
{
    float* out = (float*)d_out;
    KArgs A;
    // setup_inputs order: (x,W,b) per type:
    // 0 author(100000,128) 1 paper(250000,256) 2 venue(25000,64)
    // 3 institution(50000,128) 4 field(75000,64) 5 term(150000,128)
    const int  nrows[6] = {100000, 250000, 25000, 50000, 75000, 150000};
    const long ooff[6]  = {0L, 12800000L, 44800000L, 48000000L, 54400000L, 64000000L};
    // blocks proportional to per-type HBM bytes (sum = 2048)
    const int  blk0[7]  = {0, 273, 1297, 1348, 1485, 1639, 2048};
    for (int t = 0; t < 6; ++t) {
        A.x[t]     = (const float*)d_in[3 * t + 0];
        A.W[t]     = (const float*)d_in[3 * t + 1];
        A.b[t]     = (const float*)d_in[3 * t + 2];
        A.out[t]   = out + ooff[t];
        A.nrows[t] = nrows[t];
    }
    for (int i = 0; i < 7; ++i) A.blk0[i] = blk0[i];

    hetero_fused_kern<<<2048, 256, 0, stream>>>(A);
}

// Round 4
// 247.045 us; speedup vs baseline: 1.1057x; 1.1057x over previous
//
#include <hip/hip_runtime.h>

typedef __bf16 bf16x8 __attribute__((ext_vector_type(8)));
typedef float  f32x4  __attribute__((ext_vector_type(4)));

struct KArgs {
    const float* x[6];
    const float* W[6];
    const float* b[6];
    float*       out[6];
    int nrows[6];
    int blk0[7];   // cumulative block offsets per type
};

// Wave-autonomous, barrier-free, LDS-free, +1-chunk register prefetch.
// A = W (M = output col, bf16 in regs), B = x (N = x-row, global->reg->cvt).
// D lane map (m89): col(l15) = x-row, row(lq*4+r) = out col -> float4 stores.
//   FIN<=128: 4 waves = 2 row-groups x 2 col-halves (32 rows, 64 cols/wave)
//   FIN==256: 4 waves = 1 row-group  x 4 col-quarters (16 rows, 32 cols/wave;
//             all waves load the same x rows -> L1/L2 serves the 4x re-read)
template<int FIN>
__device__ __forceinline__ void run_type(
    const float* __restrict__ x, const float* __restrict__ W,
    const float* __restrict__ bias, float* __restrict__ out,
    int nrows, int c0, int c1)
{
    constexpr int NC   = FIN / 32;                 // k-fragments
    constexpr int T    = (FIN == 256) ? 2 : 4;     // 16-col tiles per wave
    constexpr int ROWS = (FIN == 256) ? 16 : 32;   // x-rows per chunk

    const int tid     = threadIdx.x;
    const int lane    = tid & 63;
    const int wave    = tid >> 6;
    const int l15     = lane & 15;
    const int lq      = lane >> 4;
    const int rowgrp  = (FIN == 256) ? 0 : (wave >> 1);
    const int colbase = (FIN == 256) ? (wave * 32) : ((wave & 1) * 64);

    // ---- W fragments (A operand), fp32 -> bf16 once per block
    bf16x8 Wf[NC][T];
    #pragma unroll
    for (int t = 0; t < T; ++t) {
        const int o = colbase + t * 16 + l15;      // output col = W row
        #pragma unroll
        for (int c = 0; c < NC; ++c) {
            const f32x4 w0 = *(const f32x4*)(W + (size_t)o * FIN + c * 32 + lq * 8);
            const f32x4 w1 = *(const f32x4*)(W + (size_t)o * FIN + c * 32 + lq * 8 + 4);
            bf16x8 fr;
            fr[0] = (__bf16)w0[0]; fr[1] = (__bf16)w0[1];
            fr[2] = (__bf16)w0[2]; fr[3] = (__bf16)w0[3];
            fr[4] = (__bf16)w1[0]; fr[5] = (__bf16)w1[1];
            fr[6] = (__bf16)w1[2]; fr[7] = (__bf16)w1[3];
            Wf[c][t] = fr;
        }
    }
    f32x4 bv[T];
    #pragma unroll
    for (int t = 0; t < T; ++t)
        bv[t] = *(const f32x4*)(bias + colbase + t * 16 + lq * 4);

    f32x4  fbuf[2 * NC];   // in-flight fp32 x data (next chunk)
    bf16x8 cur[NC];        // converted bf16 x data (current chunk)

    auto issue = [&](int chunk) {            // issue global loads -> fbuf
        const int xr = chunk * ROWS + rowgrp * 16 + l15;
        const int gr = (xr < nrows) ? xr : (nrows - 1);   // clamp; stores guarded
        const float* xp = x + (size_t)gr * FIN + lq * 8;
        #pragma unroll
        for (int c = 0; c < NC; ++c) {
            fbuf[2 * c]     = *(const f32x4*)(xp + c * 32);
            fbuf[2 * c + 1] = *(const f32x4*)(xp + c * 32 + 4);
        }
    };
    auto cvtall = [&]() {                    // fbuf (arrived) -> cur
        #pragma unroll
        for (int c = 0; c < NC; ++c) {
            bf16x8 b;
            b[0] = (__bf16)fbuf[2*c][0];     b[1] = (__bf16)fbuf[2*c][1];
            b[2] = (__bf16)fbuf[2*c][2];     b[3] = (__bf16)fbuf[2*c][3];
            b[4] = (__bf16)fbuf[2*c+1][0];   b[5] = (__bf16)fbuf[2*c+1][1];
            b[6] = (__bf16)fbuf[2*c+1][2];   b[7] = (__bf16)fbuf[2*c+1][3];
            cur[c] = b;
        }
    };

    issue(c0);
    cvtall();
    for (int n = c0; n < c1; ++n) {
        issue(n + 1);                        // prefetch (clamped; always safe)

        f32x4 acc[T] = {};
        #pragma unroll
        for (int c = 0; c < NC; ++c) {
            #pragma unroll
            for (int t = 0; t < T; ++t)
                acc[t] = __builtin_amdgcn_mfma_f32_16x16x32_bf16(
                    Wf[c][t], cur[c], acc[t], 0, 0, 0);
        }

        const int xr = n * ROWS + rowgrp * 16 + l15;
        if (xr < nrows) {
            float* op = out + (size_t)xr * 128 + colbase;
            #pragma unroll
            for (int t = 0; t < T; ++t)
                __builtin_nontemporal_store(acc[t] + bv[t],
                                            (f32x4*)(op + t * 16 + lq * 4));
        }

        cvtall();                            // waits for prefetch; hidden by compute
    }
}

__global__ __launch_bounds__(256, 2) void hetero_fused_kern(KArgs A)
{
    int ty = 0;
    const int bid = blockIdx.x;
    while (ty < 5 && bid >= A.blk0[ty + 1]) ++ty;
    const int lb = bid - A.blk0[ty];
    const int nb = A.blk0[ty + 1] - A.blk0[ty];

    const int nrows  = A.nrows[ty];
    const int ROWS   = (ty == 1) ? 16 : 32;
    const int chunks = (nrows + ROWS - 1) / ROWS;
    const int c0 = (int)(((long)chunks * lb) / nb);
    const int c1 = (int)(((long)chunks * (lb + 1)) / nb);
    if (c0 >= c1) return;

    switch (ty) {
        case 0: run_type<128>(A.x[0], A.W[0], A.b[0], A.out[0], nrows, c0, c1); break;
        case 1: run_type<256>(A.x[1], A.W[1], A.b[1], A.out[1], nrows, c0, c1); break;
        case 2: run_type< 64>(A.x[2], A.W[2], A.b[2], A.out[2], nrows, c0, c1); break;
        case 3: run_type<128>(A.x[3], A.W[3], A.b[3], A.out[3], nrows, c0, c1); break;
        case 4: run_type< 64>(A.x[4], A.W[4], A.b[4], A.out[4], nrows, c0, c1); break;
        case 5: run_type<128>(A.x[5], A.W[5], A.b[5], A.out[5], nrows, c0, c1); break;
    }
}

extern "C" void kernel_launch(void* const* d_in, const int* in_sizes, int n_in,
                              void* d_out, int out_size, void* d_ws, size_t ws_size,
                              hipStream_t stream)
{
    float* out = (float*)d_out;
    KArgs A;
    // setup_inputs order: (x,W,b) per type:
    // 0 author(100000,128) 1 paper(250000,256) 2 venue(25000,64)
    // 3 institution(50000,128) 4 field(75000,64) 5 term(150000,128)
    const int  nrows[6] = {100000, 250000, 25000, 50000, 75000, 150000};
    const long ooff[6]  = {0L, 12800000L, 44800000L, 48000000L, 54400000L, 64000000L};
    // blocks proportional to per-type HBM bytes (sum = 2048)
    const int  blk0[7]  = {0, 273, 1297, 1348, 1485, 1639, 2048};
    for (int t = 0; t < 6; ++t) {
        A.x[t]     = (const float*)d_in[3 * t + 0];
        A.W[t]     = (const float*)d_in[3 * t + 1];
        A.b[t]     = (const float*)d_in[3 * t + 2];
        A.out[t]   = out + ooff[t];
        A.nrows[t] = nrows[t];
    }
    for (int i = 0; i < 7; ++i) A.blk0[i] = blk0[i];

    hetero_fused_kern<<<2048, 256, 0, stream>>>(A);
}

// Round 5
// 184.179 us; speedup vs baseline: 1.4831x; 1.3413x over previous
//
#include <hip/hip_runtime.h>

typedef __bf16 bf16x4 __attribute__((ext_vector_type(4)));
typedef __bf16 bf16x8 __attribute__((ext_vector_type(8)));
typedef float  f32x4  __attribute__((ext_vector_type(4)));

struct KArgs {
    const float* x[6];
    const float* W[6];
    const float* b[6];
    float*       out[6];
    int nrows[6];
    int blk0[7];   // cumulative block offsets per type
};

// Double-buffered LDS pipeline, ONE barrier per chunk.
//   iter n: issue loads(n+1)->regs | ds_read buf[cur] -> MFMA -> store(n)
//           | (compiler vmcnt waits loads only) cvt -> ds_write buf[cur^1]
//           | __syncthreads()
// Every FIN stages 16 KB/chunk: ROWS = 8192/FIN (128/64/32 rows).
// A = W (M = out col, bf16 regs), B = x (N = x row, LDS XOR-swizzled).
// D lane map (m89): col(l15) = x-row, row(lq*4+r) = out col -> float4 stores.
template<int FIN>
__device__ __forceinline__ void run_type(
    const float* __restrict__ x, const float* __restrict__ W,
    const float* __restrict__ bias, float* __restrict__ out,
    int nrows, int c0, int c1, __bf16* __restrict__ lds)
{
    constexpr int ROWS = 8192 / FIN;   // rows per chunk
    constexpr int NC   = FIN / 32;     // k-fragments
    constexpr int MT   = ROWS / 16;    // m-tiles per chunk
    constexpr int S    = FIN * 2;      // LDS row stride, bytes
    constexpr int QPR  = FIN / 4;      // float4 per row

    const int tid     = threadIdx.x;
    const int lane    = tid & 63;
    const int wave    = tid >> 6;
    const int l15     = lane & 15;
    const int lq      = lane >> 4;
    const int colbase = wave * 32;     // each wave owns 32 output cols

    // ---- W fragments (A operand), fp32 -> bf16 once per block
    bf16x8 Wf[NC][2];
    f32x4  bv[2];
    #pragma unroll
    for (int t = 0; t < 2; ++t) {
        const int o = colbase + t * 16 + l15;          // out col = W row
        #pragma unroll
        for (int c = 0; c < NC; ++c) {
            const f32x4 w0 = *(const f32x4*)(W + (size_t)o * FIN + c * 32 + lq * 8);
            const f32x4 w1 = *(const f32x4*)(W + (size_t)o * FIN + c * 32 + lq * 8 + 4);
            bf16x8 fr;
            fr[0] = (__bf16)w0[0]; fr[1] = (__bf16)w0[1];
            fr[2] = (__bf16)w0[2]; fr[3] = (__bf16)w0[3];
            fr[4] = (__bf16)w1[0]; fr[5] = (__bf16)w1[1];
            fr[6] = (__bf16)w1[2]; fr[7] = (__bf16)w1[3];
            Wf[c][t] = fr;
        }
        bv[t] = *(const f32x4*)(bias + colbase + t * 16 + lq * 4);
    }

    f32x4 fbuf[8];   // in-flight fp32 x data for the NEXT chunk

    auto issue = [&](int chunk) {       // global -> regs, no wait
        #pragma unroll
        for (int i = 0; i < 8; ++i) {
            const int u  = tid + i * 256;
            const int r  = u / QPR;
            const int kq = u % QPR;
            int gr = chunk * ROWS + r;
            if (gr >= nrows) gr = nrows - 1;           // clamp; stores guarded
            fbuf[i] = __builtin_nontemporal_load(
                (const f32x4*)(x + (size_t)gr * FIN + kq * 4));
        }
    };
    auto commit = [&](int b) {          // cvt + ds_write (waits loads via vmcnt)
        __bf16* dst = lds + b * 8192;
        #pragma unroll
        for (int i = 0; i < 8; ++i) {
            const int u  = tid + i * 256;
            const int r  = u / QPR;
            const int kq = u % QPR;
            bf16x4 q;
            q[0] = (__bf16)fbuf[i][0]; q[1] = (__bf16)fbuf[i][1];
            q[2] = (__bf16)fbuf[i][2]; q[3] = (__bf16)fbuf[i][3];
            const int byte = (r * S + kq * 8) ^ ((r & 7) << 4);
            *(bf16x4*)((char*)dst + byte) = q;
        }
    };

    issue(c0);
    commit(0);
    __syncthreads();

    int cur = 0;
    for (int n = c0; n < c1; ++n) {
        const bool more = (n + 1 < c1);
        if (more) issue(n + 1);         // prefetch: consumed after compute

        const __bf16* src = lds + cur * 8192;
        #pragma unroll
        for (int mt = 0; mt < MT; ++mt) {
            const int row = mt * 16 + l15;
            f32x4 acc0 = {0.f, 0.f, 0.f, 0.f};
            f32x4 acc1 = {0.f, 0.f, 0.f, 0.f};
            #pragma unroll
            for (int c = 0; c < NC; ++c) {
                const int byte = (row * S + c * 64 + lq * 16) ^ ((row & 7) << 4);
                const bf16x8 xf = *(const bf16x8*)((const char*)src + byte);
                acc0 = __builtin_amdgcn_mfma_f32_16x16x32_bf16(Wf[c][0], xf, acc0, 0, 0, 0);
                acc1 = __builtin_amdgcn_mfma_f32_16x16x32_bf16(Wf[c][1], xf, acc1, 0, 0, 0);
            }
            const int xrow = n * ROWS + mt * 16 + l15;
            if (xrow < nrows) {
                float* op = out + (size_t)xrow * 128 + colbase;
                __builtin_nontemporal_store(acc0 + bv[0], (f32x4*)(op + lq * 4));
                __builtin_nontemporal_store(acc1 + bv[1], (f32x4*)(op + 16 + lq * 4));
            }
        }

        if (more) commit(cur ^ 1);
        __syncthreads();
        cur ^= 1;
    }
}

__global__ __launch_bounds__(256, 3) void hetero_fused_kern(KArgs A)
{
    __shared__ __bf16 lds[2 * 8192];   // 32 KiB: double buffer

    int ty = 0;
    const int bid = blockIdx.x;
    while (ty < 5 && bid >= A.blk0[ty + 1]) ++ty;
    const int lb = bid - A.blk0[ty];
    const int nb = A.blk0[ty + 1] - A.blk0[ty];

    const int nrows  = A.nrows[ty];
    const int ROWS   = (ty == 1) ? 32 : ((ty == 2 || ty == 4) ? 128 : 64);
    const int chunks = (nrows + ROWS - 1) / ROWS;
    const int c0 = (int)(((long)chunks * lb) / nb);
    const int c1 = (int)(((long)chunks * (lb + 1)) / nb);
    if (c0 >= c1) return;

    switch (ty) {
        case 0: run_type<128>(A.x[0], A.W[0], A.b[0], A.out[0], nrows, c0, c1, lds); break;
        case 1: run_type<256>(A.x[1], A.W[1], A.b[1], A.out[1], nrows, c0, c1, lds); break;
        case 2: run_type< 64>(A.x[2], A.W[2], A.b[2], A.out[2], nrows, c0, c1, lds); break;
        case 3: run_type<128>(A.x[3], A.W[3], A.b[3], A.out[3], nrows, c0, c1, lds); break;
        case 4: run_type< 64>(A.x[4], A.W[4], A.b[4], A.out[4], nrows, c0, c1, lds); break;
        case 5: run_type<128>(A.x[5], A.W[5], A.b[5], A.out[5], nrows, c0, c1, lds); break;
    }
}

extern "C" void kernel_launch(void* const* d_in, const int* in_sizes, int n_in,
                              void* d_out, int out_size, void* d_ws, size_t ws_size,
                              hipStream_t stream)
{
    float* out = (float*)d_out;
    KArgs A;
    // setup_inputs order: (x,W,b) per type:
    // 0 author(100000,128) 1 paper(250000,256) 2 venue(25000,64)
    // 3 institution(50000,128) 4 field(75000,64) 5 term(150000,128)
    const int  nrows[6] = {100000, 250000, 25000, 50000, 75000, 150000};
    const long ooff[6]  = {0L, 12800000L, 44800000L, 48000000L, 54400000L, 64000000L};
    // 768 blocks = 3/CU exactly; split proportional to per-type HBM bytes
    const int  blk0[7]  = {0, 102, 486, 505, 556, 614, 768};
    for (int t = 0; t < 6; ++t) {
        A.x[t]     = (const float*)d_in[3 * t + 0];
        A.W[t]     = (const float*)d_in[3 * t + 1];
        A.b[t]     = (const float*)d_in[3 * t + 2];
        A.out[t]   = out + ooff[t];
        A.nrows[t] = nrows[t];
    }
    for (int i = 0; i < 7; ++i) A.blk0[i] = blk0[i];

    hetero_fused_kern<<<768, 256, 0, stream>>>(A);
}